// Round 1
// 645.067 us; speedup vs baseline: 1.1154x; 1.1154x over previous
//
#include <hip/hip_runtime.h>
#include <math.h>

#define BB 8
#define VV 32000
#define SS 512
#define NCHUNK 128
#define CHUNK 250               // NCHUNK * CHUNK == VV; grid = 8*128 = 1024 = 4 blocks/CU exactly
#define NCOL (BB * SS)          // 4096
#define NGRAM 4
#define PP (SS - NGRAM)         // 508

typedef float vfloat4 __attribute__((ext_vector_type(4)));

// Kernel A: per-column (b,s) partial stats (max, argmax, sum-exp) over a V-chunk.
// 1024 blocks (exactly 4/CU, 128/XCD), 256 threads. Wave reads 1 KB contiguous.
// exp2 via raw v_exp_f32 builtin; nontemporal streaming loads.
// Block 0 thread 0 also zeroes the output (stream order puts this before finalize).
__global__ __launch_bounds__(256) void colstats_kernel(const float* __restrict__ pred,
                                                       float2* __restrict__ pms,
                                                       int* __restrict__ pidx,
                                                       float* __restrict__ out) {
    const int bid = blockIdx.x;
    if (bid == 0 && threadIdx.x == 0) out[0] = 0.0f;
    const int b   = bid >> 7;           // NCHUNK = 128
    const int c   = bid & 127;
    const int tid = threadIdx.x;
    const int vo  = tid >> 7;           // 0/1: which of the 2 rows per iteration
    const int s   = (tid & 127) << 2;   // 0..508
    const int v0  = c * CHUNK;

    float m0 = -INFINITY, m1 = -INFINITY, m2 = -INFINITY, m3 = -INFINITY;
    float a0 = 0.f, a1 = 0.f, a2 = 0.f, a3 = 0.f;
    int   i0 = 0, i1 = 0, i2 = 0, i3 = 0;

    const float L2E = 1.4426950408889634f;
    const vfloat4* ptr = (const vfloat4*)(pred + ((size_t)(b * VV + v0 + vo)) * SS + s);
    int v = v0 + vo;
#pragma unroll 5
    for (int k = 0; k < CHUNK / 2; ++k) {   // 125 iterations, 5 | 125
        const vfloat4 x = __builtin_nontemporal_load(ptr);
        ptr += (2 * SS) / 4;
        a0 += __builtin_amdgcn_exp2f(x.x * L2E);
        a1 += __builtin_amdgcn_exp2f(x.y * L2E);
        a2 += __builtin_amdgcn_exp2f(x.z * L2E);
        a3 += __builtin_amdgcn_exp2f(x.w * L2E);
        if (x.x > m0) { m0 = x.x; i0 = v; }
        if (x.y > m1) { m1 = x.y; i1 = v; }
        if (x.z > m2) { m2 = x.z; i2 = v; }
        if (x.w > m3) { m3 = x.w; i3 = v; }
        v += 2;
    }

    __shared__ float smax[256][4];
    __shared__ float ssum[256][4];
    __shared__ int   sidx[256][4];
    smax[tid][0] = m0; smax[tid][1] = m1; smax[tid][2] = m2; smax[tid][3] = m3;
    ssum[tid][0] = a0; ssum[tid][1] = a1; ssum[tid][2] = a2; ssum[tid][3] = a3;
    sidx[tid][0] = i0; sidx[tid][1] = i1; sidx[tid][2] = i2; sidx[tid][3] = i3;
    __syncthreads();

    if (tid < 128) {
        const int o = tid + 128;
        float m[4]  = {smax[tid][0], smax[tid][1], smax[tid][2], smax[tid][3]};
        float a[4]  = {ssum[tid][0], ssum[tid][1], ssum[tid][2], ssum[tid][3]};
        int   ix[4] = {sidx[tid][0], sidx[tid][1], sidx[tid][2], sidx[tid][3]};
#pragma unroll
        for (int j = 0; j < 4; ++j) {
            const float om = smax[o][j];
            const int   oi = sidx[o][j];
            a[j] += ssum[o][j];
            if (om > m[j] || (om == m[j] && oi < ix[j])) { m[j] = om; ix[j] = oi; }
        }
        const size_t ob = (size_t)c * NCOL + (size_t)b * SS + (size_t)(tid << 2);
#pragma unroll
        for (int j = 0; j < 4; ++j) {
            float2 t; t.x = m[j]; t.y = a[j];
            pms[ob + j]  = t;
            pidx[ob + j] = ix[j];
        }
    }
}

// Kernel B: combine 128 chunk-partials per column across 128 blocks (vs 8 before).
// Block = 32 columns x 8 chunk-slices (256 threads). Each thread reduces 16 chunks,
// LDS tree over slices, then computes token + penalty directly.
__global__ __launch_bounds__(256) void combine_kernel(const float2* __restrict__ pms,
                                                      const int* __restrict__ pidx,
                                                      int* __restrict__ tok,
                                                      float* __restrict__ pen) {
    const int tid = threadIdx.x;
    const int cl  = tid & 31;                  // column within block
    const int sl  = tid >> 5;                  // chunk slice 0..7
    const int col = (blockIdx.x << 5) + cl;    // global column = b*SS + s

    float m = -INFINITY, sum = 0.f;
    int   idx = 0x7fffffff;
#pragma unroll 4
    for (int c = sl * 16; c < sl * 16 + 16; ++c) {
        const int off = c * NCOL + col;
        const float2 ms = pms[off];
        const int    ci = pidx[off];
        sum += ms.y;
        if (ms.x > m || (ms.x == m && ci < idx)) { m = ms.x; idx = ci; }
    }

    __shared__ float sm[8][32];
    __shared__ float ss[8][32];
    __shared__ int   si[8][32];
    sm[sl][cl] = m; ss[sl][cl] = sum; si[sl][cl] = idx;
    __syncthreads();

    if (tid < 32) {
        float M = sm[0][tid], S = ss[0][tid];
        int   I = si[0][tid];
#pragma unroll
        for (int q = 1; q < 8; ++q) {
            const float om = sm[q][tid];
            const int   oi = si[q][tid];
            S += ss[q][tid];
            if (om > M || (om == M && oi < I)) { M = om; I = oi; }
        }
        const float lprob = M - logf(S);       // log_softmax at argmax
        const float p = expf(lprob);
        float om1 = 1.0f - p;
        if (om1 < 1e-20f) om1 = 1e-20f;
        const int g = (blockIdx.x << 5) + tid;
        tok[g] = I;
        pen[g] = -logf(om1);
    }
}

// Kernel C: n-gram repeat mask + masked loss. One block per batch, 512 threads.
// 4-gram packed injectively into u64 (tokens < 32768): 1 ds_read_b64 + cmp per
// candidate, branchless OR-accumulate (early break never fires on random tokens).
__global__ __launch_bounds__(512) void finalize_mask_kernel(const int* __restrict__ tok,
                                                            const float* __restrict__ pen,
                                                            float* __restrict__ out) {
    const int b   = blockIdx.x;
    const int tid = threadIdx.x;
    const int g   = b * SS + tid;
    const int   t  = tok[g];
    const float pv = pen[g];

    __shared__ int tk[SS];
    __shared__ unsigned long long hh[PP];
    __shared__ int rep[SS];
    tk[tid]  = t;
    rep[tid] = 0;
    __syncthreads();

    if (tid < PP) {
        const unsigned long long h = (unsigned long long)tk[tid]
            | ((unsigned long long)tk[tid + 1] << 15)
            | ((unsigned long long)tk[tid + 2] << 30)
            | ((unsigned long long)tk[tid + 3] << 45);
        hh[tid] = h;
    }
    __syncthreads();

    if (tid < PP) {
        const unsigned long long h = hh[tid];
        int r = 0;
#pragma unroll 4
        for (int j = 0; j < tid; ++j) r |= (hh[j] == h);
        rep[tid] = r;
    }
    __syncthreads();

    float local = 0.f;
    {
        int msk = 0;
#pragma unroll
        for (int k = 0; k < NGRAM; ++k) {
            const int i = tid - k;
            if (i >= 0 && i < PP && rep[i]) msk = 1;
        }
        if (msk) local = pv;
    }

    for (int off = 32; off > 0; off >>= 1) local += __shfl_down(local, off, 64);
    __shared__ float wsum[8];
    const int lane = tid & 63, wid = tid >> 6;
    if (lane == 0) wsum[wid] = local;
    __syncthreads();
    if (tid == 0) {
        float tt = 0.f;
#pragma unroll
        for (int w = 0; w < 8; ++w) tt += wsum[w];
        atomicAdd(out, tt * (1.0f / (float)BB));
    }
}

extern "C" void kernel_launch(void* const* d_in, const int* in_sizes, int n_in,
                              void* d_out, int out_size, void* d_ws, size_t ws_size,
                              hipStream_t stream) {
    const float* pred = (const float*)d_in[0];
    float* out = (float*)d_out;
    char* ws = (char*)d_ws;

    const size_t partN = (size_t)NCHUNK * NCOL;            // 524288
    float2* pms  = (float2*)ws;                            // 4 MB
    int*    pidx = (int*)(ws + partN * 8);                 // 2 MB
    int*    tok  = (int*)(ws + partN * 12);                // 16 KB
    float*  pen  = (float*)(ws + partN * 12 + NCOL * 4);   // 16 KB

    colstats_kernel<<<BB * NCHUNK, 256, 0, stream>>>(pred, pms, pidx, out);
    combine_kernel<<<NCOL / 32, 256, 0, stream>>>(pms, pidx, tok, pen);
    finalize_mask_kernel<<<BB, 512, 0, stream>>>(tok, pen, out);
}